// Round 1
// baseline (291.086 us; speedup 1.0000x reference)
//
#include <hip/hip_runtime.h>
#include <hip/hip_bf16.h>

// BatchedExponentialOrthogonalization: res = sum_{i=0}^{6} S^i / i!,  S = 0.5(w - w^T)
// w: (512, 256, 256) fp32.  Horner: T = I + S/6; then T = I + (S/k)*T for k=5,4,3,2,1.
// Strategy: prep kernel builds S in bf16 (one rounding from exact fp32) into d_ws
// (needs 64 MB of ws). Main kernel: per (batch, 64-col block) workgroup, 4 waves;
// each wave holds its 64 rows of S as MFMA A-fragments in registers for all 5
// iterations; T lives in LDS transposed [col][k] bf16 with XOR bank swizzle.

#define NB 512
#define NN 256

typedef __attribute__((ext_vector_type(8))) short bf16x8;
typedef __attribute__((ext_vector_type(4))) float f32x4;

__device__ __forceinline__ unsigned short f2bf(float x) {
  union { float f; unsigned int u; } v; v.f = x;
  unsigned int r = v.u + 0x7fffu + ((v.u >> 16) & 1u);  // RTNE
  return (unsigned short)(r >> 16);
}
__device__ __forceinline__ float bf2f(unsigned short u) {
  union { unsigned int u; float f; } v; v.u = ((unsigned int)u) << 16; return v.f;
}

// ---------------- prep: S = 0.5*(w - w^T) in bf16, exact-fp32 before one rounding ----
__global__ __launch_bounds__(256) void skew_prep_kernel(const float* __restrict__ w,
                                                        unsigned short* __restrict__ s) {
  const int b = blockIdx.x;
  const float* wb = w + (size_t)b * NN * NN;
  unsigned short* sb = s + (size_t)b * NN * NN;
  __shared__ float ta[64][65];
  __shared__ float tb[64][65];
  const int tid = threadIdx.x;
  for (int ti = 0; ti < 4; ++ti) {
    for (int tj = ti; tj < 4; ++tj) {
      #pragma unroll
      for (int e = 0; e < 16; ++e) {
        int idx = e * 256 + tid;
        int r = idx >> 6, c = idx & 63;
        ta[r][c] = wb[(ti * 64 + r) * NN + tj * 64 + c];
      }
      if (ti != tj) {
        #pragma unroll
        for (int e = 0; e < 16; ++e) {
          int idx = e * 256 + tid;
          int r = idx >> 6, c = idx & 63;
          tb[r][c] = wb[(tj * 64 + r) * NN + ti * 64 + c];
        }
      }
      __syncthreads();
      #pragma unroll
      for (int e = 0; e < 16; ++e) {
        int idx = e * 256 + tid;
        int r = idx >> 6, c = idx & 63;
        float av = ta[r][c];
        float bt = (ti == tj) ? ta[c][r] : tb[c][r];
        sb[(ti * 64 + r) * NN + tj * 64 + c] = f2bf(0.5f * (av - bt));
        if (ti != tj) {
          sb[(tj * 64 + r) * NN + ti * 64 + c] = f2bf(0.5f * (tb[r][c] - ta[c][r]));
        }
      }
      __syncthreads();
    }
  }
}

// ---------------- main: Horner chain, S-rows in registers, T in LDS ------------------
__global__ __launch_bounds__(256, 2) void expm_main_kernel(const unsigned short* __restrict__ s,
                                                           float* __restrict__ out) {
  const int bid = blockIdx.x;
  const int b = bid >> 2;
  const int cb = bid & 3;
  const int tid = threadIdx.x;
  const int wv = tid >> 6;
  const int l = tid & 63;
  const int l15 = l & 15;
  const int l4 = l >> 4;

  const unsigned short* sb = s + (size_t)b * NN * NN;
  // T transposed: [col 0..63][k 0..255] bf16, byte addr = col*512 + ((2k) ^ ((col&7)<<4))
  __shared__ alignas(16) unsigned char Tl[64 * NN * 2];

  // --- A fragments: wave wv owns S rows [64*wv, 64*wv+64), persistent in registers ---
  bf16x8 a[4][8];
  const int rbase = wv * 64;
  #pragma unroll
  for (int mf = 0; mf < 4; ++mf) {
    const bf16x8* p = (const bf16x8*)(sb + (size_t)(rbase + 16 * mf + l15) * NN);
    #pragma unroll
    for (int ks = 0; ks < 8; ++ks) a[mf][ks] = p[4 * ks + l4];
  }

  // --- T init: T = I + S/6 (columns cb*64 .. cb*64+63 of S) ---
  {
    const int c = tid & 63;
    const int kg = tid >> 6;
    const int gcol = cb * 64 + c;
    const int swz = (c & 7) << 4;
    #pragma unroll
    for (int kc = 0; kc < 8; ++kc) {
      const int k0 = kg * 64 + kc * 8;
      unsigned int pk0, pk1, pk2, pk3;
      {
        float va, vb2;
        va  = bf2f(sb[(size_t)(k0 + 0) * NN + gcol]) * (1.0f / 6.0f) + ((k0 + 0 == gcol) ? 1.0f : 0.0f);
        vb2 = bf2f(sb[(size_t)(k0 + 1) * NN + gcol]) * (1.0f / 6.0f) + ((k0 + 1 == gcol) ? 1.0f : 0.0f);
        pk0 = (unsigned int)f2bf(va) | ((unsigned int)f2bf(vb2) << 16);
        va  = bf2f(sb[(size_t)(k0 + 2) * NN + gcol]) * (1.0f / 6.0f) + ((k0 + 2 == gcol) ? 1.0f : 0.0f);
        vb2 = bf2f(sb[(size_t)(k0 + 3) * NN + gcol]) * (1.0f / 6.0f) + ((k0 + 3 == gcol) ? 1.0f : 0.0f);
        pk1 = (unsigned int)f2bf(va) | ((unsigned int)f2bf(vb2) << 16);
        va  = bf2f(sb[(size_t)(k0 + 4) * NN + gcol]) * (1.0f / 6.0f) + ((k0 + 4 == gcol) ? 1.0f : 0.0f);
        vb2 = bf2f(sb[(size_t)(k0 + 5) * NN + gcol]) * (1.0f / 6.0f) + ((k0 + 5 == gcol) ? 1.0f : 0.0f);
        pk2 = (unsigned int)f2bf(va) | ((unsigned int)f2bf(vb2) << 16);
        va  = bf2f(sb[(size_t)(k0 + 6) * NN + gcol]) * (1.0f / 6.0f) + ((k0 + 6 == gcol) ? 1.0f : 0.0f);
        vb2 = bf2f(sb[(size_t)(k0 + 7) * NN + gcol]) * (1.0f / 6.0f) + ((k0 + 7 == gcol) ? 1.0f : 0.0f);
        pk3 = (unsigned int)f2bf(va) | ((unsigned int)f2bf(vb2) << 16);
      }
      const int byte = c * 512 + ((k0 * 2) ^ swz);
      uint4 val; val.x = pk0; val.y = pk1; val.z = pk2; val.w = pk3;
      *(uint4*)(&Tl[byte]) = val;
    }
  }
  __syncthreads();

  float* const outb = out + (size_t)b * NN * NN + cb * 64;

  for (int it = 0; it < 5; ++it) {
    const float coef = (it == 0) ? 0.2f : (it == 1) ? 0.25f : (it == 2) ? (1.0f / 3.0f)
                     : (it == 3) ? 0.5f : 1.0f;
    f32x4 acc[4][4];
    #pragma unroll
    for (int mf = 0; mf < 4; ++mf)
      #pragma unroll
      for (int nf = 0; nf < 4; ++nf) {
        f32x4 z = {0.0f, 0.0f, 0.0f, 0.0f};
        acc[mf][nf] = z;
      }

    #pragma unroll
    for (int ks = 0; ks < 8; ++ks) {
      bf16x8 bfr[4];
      #pragma unroll
      for (int nf = 0; nf < 4; ++nf) {
        const int col = 16 * nf + l15;
        const int byte = col * 512 + (((32 * ks + 8 * l4) * 2) ^ ((col & 7) << 4));
        bfr[nf] = *(const bf16x8*)(&Tl[byte]);
      }
      #pragma unroll
      for (int mf = 0; mf < 4; ++mf)
        #pragma unroll
        for (int nf = 0; nf < 4; ++nf)
          acc[mf][nf] = __builtin_amdgcn_mfma_f32_16x16x32_bf16(a[mf][ks], bfr[nf], acc[mf][nf], 0, 0, 0);
    }
    __syncthreads();  // all waves done reading T_old
    if (it < 4) {
      #pragma unroll
      for (int mf = 0; mf < 4; ++mf) {
        #pragma unroll
        for (int nf = 0; nf < 4; ++nf) {
          const int col = 16 * nf + l15;
          const int gcol = cb * 64 + col;
          const int row0 = rbase + 16 * mf + 4 * l4;
          float v0 = coef * acc[mf][nf][0] + ((row0 + 0 == gcol) ? 1.0f : 0.0f);
          float v1 = coef * acc[mf][nf][1] + ((row0 + 1 == gcol) ? 1.0f : 0.0f);
          float v2 = coef * acc[mf][nf][2] + ((row0 + 2 == gcol) ? 1.0f : 0.0f);
          float v3 = coef * acc[mf][nf][3] + ((row0 + 3 == gcol) ? 1.0f : 0.0f);
          unsigned int lo = (unsigned int)f2bf(v0) | ((unsigned int)f2bf(v1) << 16);
          unsigned int hi = (unsigned int)f2bf(v2) | ((unsigned int)f2bf(v3) << 16);
          const int byte = col * 512 + ((row0 * 2) ^ ((col & 7) << 4));
          uint2 val; val.x = lo; val.y = hi;
          *(uint2*)(&Tl[byte]) = val;
        }
      }
      __syncthreads();  // T_new visible before next iteration's reads
    } else {
      // final iteration: write res = I + S*T in fp32 straight to global
      #pragma unroll
      for (int mf = 0; mf < 4; ++mf) {
        #pragma unroll
        for (int nf = 0; nf < 4; ++nf) {
          const int col = 16 * nf + l15;
          const int gcol = cb * 64 + col;
          const int row0 = rbase + 16 * mf + 4 * l4;
          #pragma unroll
          for (int j = 0; j < 4; ++j) {
            float v = acc[mf][nf][j] + ((row0 + j == gcol) ? 1.0f : 0.0f);
            outb[(size_t)(row0 + j) * NN + col] = v;
          }
        }
      }
    }
  }
}

extern "C" void kernel_launch(void* const* d_in, const int* in_sizes, int n_in,
                              void* d_out, int out_size, void* d_ws, size_t ws_size,
                              hipStream_t stream) {
  const float* w = (const float*)d_in[0];
  float* out = (float*)d_out;
  unsigned short* sws = (unsigned short*)d_ws;  // needs 512*256*256*2 = 64 MB
  skew_prep_kernel<<<dim3(NB), dim3(256), 0, stream>>>(w, sws);
  expm_main_kernel<<<dim3(NB * 4), dim3(256), 0, stream>>>(sws, out);
}

// Round 2
// 200.990 us; speedup vs baseline: 1.4483x; 1.4483x over previous
//
#include <hip/hip_runtime.h>
#include <hip/hip_bf16.h>

// BatchedExponentialOrthogonalization: res = sum_{i=0}^{6} S^i / i!,  S = 0.5(w - w^T)
// w: (512, 256, 256) fp32.  Horner: T = I + S/6; then T = I + (S/k)*T for k=5,4,3,2,1.
// prep: 5120 tile-pair blocks build S in bf16 into d_ws (64 MB), reading w exactly once.
// main: per (batch, 64-col block) workgroup, 4 waves; wave wv holds S rows
// [64wv,64wv+64) as MFMA A-fragments in registers for all 5 iterations; T lives in
// LDS transposed [col][k] bf16 with XOR bank swizzle. XCD-aware block mapping puts
// all 4 col-blocks of a batch on one XCD so S is fetched from HBM once per batch.

#define NB 512
#define NN 256

typedef __attribute__((ext_vector_type(8))) short bf16x8;
typedef __attribute__((ext_vector_type(4))) float f32x4;

__device__ __forceinline__ unsigned short f2bf(float x) {
  union { float f; unsigned int u; } v; v.f = x;
  unsigned int r = v.u + 0x7fffu + ((v.u >> 16) & 1u);  // RTNE
  return (unsigned short)(r >> 16);
}
__device__ __forceinline__ float bf2f(unsigned short u) {
  union { unsigned int u; float f; } v; v.u = ((unsigned int)u) << 16; return v.f;
}
__device__ __forceinline__ unsigned int pk2bf(float lo, float hi) {
  __hip_bfloat162 h;
  h.x = __float2bfloat16(lo);
  h.y = __float2bfloat16(hi);
  union { __hip_bfloat162 h; unsigned int u; } c; c.h = h;
  return c.u;
}

// ---------------- prep: S = 0.5*(w - w^T) in bf16; one block per 64x64 tile-pair ----
__global__ __launch_bounds__(256) void skew_prep_kernel(const float* __restrict__ w,
                                                        unsigned short* __restrict__ s) {
  static const int TI[10] = {0, 0, 0, 0, 1, 1, 1, 2, 2, 3};
  static const int TJ[10] = {0, 1, 2, 3, 1, 2, 3, 2, 3, 3};
  const int blk = blockIdx.x;
  const int b = blk / 10;
  const int p = blk - b * 10;
  const int ti = TI[p], tj = TJ[p];
  const float* wb = w + (size_t)b * NN * NN;
  unsigned short* sb = s + (size_t)b * NN * NN;
  __shared__ float ta[64][65];
  __shared__ float tb[64][65];
  const int tid = threadIdx.x;
  const int r = tid >> 4;        // 0..15 row group base (we loop 4 row-strides of 16)
  const int c4 = tid & 15;       // float4 column index

  #pragma unroll
  for (int e = 0; e < 4; ++e) {
    const int rr = e * 16 + r;
    float4 v = *(const float4*)&wb[(size_t)(ti * 64 + rr) * NN + tj * 64 + c4 * 4];
    ta[rr][c4 * 4 + 0] = v.x; ta[rr][c4 * 4 + 1] = v.y;
    ta[rr][c4 * 4 + 2] = v.z; ta[rr][c4 * 4 + 3] = v.w;
  }
  if (ti != tj) {
    #pragma unroll
    for (int e = 0; e < 4; ++e) {
      const int rr = e * 16 + r;
      float4 v = *(const float4*)&wb[(size_t)(tj * 64 + rr) * NN + ti * 64 + c4 * 4];
      tb[rr][c4 * 4 + 0] = v.x; tb[rr][c4 * 4 + 1] = v.y;
      tb[rr][c4 * 4 + 2] = v.z; tb[rr][c4 * 4 + 3] = v.w;
    }
  }
  __syncthreads();

  #pragma unroll
  for (int e = 0; e < 4; ++e) {
    const int rr = e * 16 + r;
    // tile (ti,tj): 0.5*(A[r][c] - B[c][r])   (B = A when diagonal)
    {
      unsigned short o[4];
      #pragma unroll
      for (int j = 0; j < 4; ++j) {
        const int cc = c4 * 4 + j;
        float av = ta[rr][cc];
        float bt = (ti == tj) ? ta[cc][rr] : tb[cc][rr];
        o[j] = f2bf(0.5f * (av - bt));
      }
      *(ushort4*)&sb[(size_t)(ti * 64 + rr) * NN + tj * 64 + c4 * 4] =
          make_ushort4(o[0], o[1], o[2], o[3]);
    }
    if (ti != tj) {
      unsigned short o[4];
      #pragma unroll
      for (int j = 0; j < 4; ++j) {
        const int cc = c4 * 4 + j;
        o[j] = f2bf(0.5f * (tb[rr][cc] - ta[cc][rr]));
      }
      *(ushort4*)&sb[(size_t)(tj * 64 + rr) * NN + ti * 64 + c4 * 4] =
          make_ushort4(o[0], o[1], o[2], o[3]);
    }
  }
}

// ---------------- main: Horner chain, S-rows in registers, T in LDS ------------------
__global__ __launch_bounds__(256, 2) void expm_main_kernel(const unsigned short* __restrict__ s,
                                                           float* __restrict__ out) {
  // XCD-aware decode: all 4 col-blocks of batch b share (g mod 8) -> same XCD L2.
  const int g = blockIdx.x;
  const int b = ((g >> 5) << 3) | (g & 7);
  const int cb = (g >> 3) & 3;
  const int tid = threadIdx.x;
  const int wv = tid >> 6;
  const int l = tid & 63;
  const int l15 = l & 15;
  const int l4 = l >> 4;

  const unsigned short* sb = s + (size_t)b * NN * NN;
  // T transposed: [col 0..63][k 0..255] bf16, byte addr = col*512 + ((2k) ^ ((col&7)<<4))
  __shared__ alignas(16) unsigned char Tl[64 * NN * 2];

  // --- A fragments: wave wv owns S rows [64*wv, 64*wv+64), persistent in registers ---
  bf16x8 a[4][8];
  const int rbase = wv * 64;
  #pragma unroll
  for (int mf = 0; mf < 4; ++mf) {
    const bf16x8* p = (const bf16x8*)(sb + (size_t)(rbase + 16 * mf + l15) * NN);
    #pragma unroll
    for (int ks = 0; ks < 8; ++ks) a[mf][ks] = p[4 * ks + l4];
  }

  // --- T init from registers: T[k][gcol] = (k==gcol) - S[gcol][k]/6 (skew symmetry).
  // Only wave cb holds rows gcol = cb*64 .. cb*64+63 in its A fragments.
  if (wv == cb) {
    #pragma unroll
    for (int mf = 0; mf < 4; ++mf) {
      const int lc = 16 * mf + l15;          // local col in T == local row in this wave
      const int gcol = rbase + lc;           // global col (== global row held)
      const int swz = (lc & 7) << 4;
      #pragma unroll
      for (int ks = 0; ks < 8; ++ks) {
        const bf16x8 fr = a[mf][ks];
        const int k0 = 32 * ks + 8 * l4;     // global k of fr[0]
        unsigned int pk[4];
        #pragma unroll
        for (int q = 0; q < 4; ++q) {
          float v0 = (-1.0f / 6.0f) * bf2f((unsigned short)fr[2 * q]);
          float v1 = (-1.0f / 6.0f) * bf2f((unsigned short)fr[2 * q + 1]);
          if (k0 + 2 * q == gcol) v0 += 1.0f;
          if (k0 + 2 * q + 1 == gcol) v1 += 1.0f;
          pk[q] = pk2bf(v0, v1);
        }
        const int byte = lc * 512 + ((2 * k0) ^ swz);
        uint4 val; val.x = pk[0]; val.y = pk[1]; val.z = pk[2]; val.w = pk[3];
        *(uint4*)(&Tl[byte]) = val;
      }
    }
  }
  __syncthreads();

  float* const outb = out + (size_t)b * NN * NN + cb * 64;
  const bool diagw = (wv == cb);

  for (int it = 0; it < 5; ++it) {
    const float coef = (it == 0) ? 0.2f : (it == 1) ? 0.25f : (it == 2) ? (1.0f / 3.0f)
                     : (it == 3) ? 0.5f : 1.0f;
    f32x4 acc[4][4];
    #pragma unroll
    for (int mf = 0; mf < 4; ++mf)
      #pragma unroll
      for (int nf = 0; nf < 4; ++nf) {
        f32x4 z = {0.0f, 0.0f, 0.0f, 0.0f};
        acc[mf][nf] = z;
      }

    #pragma unroll
    for (int ks = 0; ks < 8; ++ks) {
      bf16x8 bfr[4];
      #pragma unroll
      for (int nf = 0; nf < 4; ++nf) {
        const int col = 16 * nf + l15;
        const int byte = col * 512 + (((32 * ks + 8 * l4) * 2) ^ ((col & 7) << 4));
        bfr[nf] = *(const bf16x8*)(&Tl[byte]);
      }
      #pragma unroll
      for (int mf = 0; mf < 4; ++mf)
        #pragma unroll
        for (int nf = 0; nf < 4; ++nf)
          acc[mf][nf] = __builtin_amdgcn_mfma_f32_16x16x32_bf16(a[mf][ks], bfr[nf], acc[mf][nf], 0, 0, 0);
    }
    __syncthreads();  // all waves done reading T_old
    if (it < 4) {
      #pragma unroll
      for (int mf = 0; mf < 4; ++mf) {
        #pragma unroll
        for (int nf = 0; nf < 4; ++nf) {
          const int col = 16 * nf + l15;
          const int row0l = 16 * mf + 4 * l4;  // local row (within wave's 64)
          float v0 = coef * acc[mf][nf][0];
          float v1 = coef * acc[mf][nf][1];
          float v2 = coef * acc[mf][nf][2];
          float v3 = coef * acc[mf][nf][3];
          if (diagw && mf == nf) {
            // identity possible only when global row == global col
            if (row0l + 0 == col) v0 += 1.0f;
            if (row0l + 1 == col) v1 += 1.0f;
            if (row0l + 2 == col) v2 += 1.0f;
            if (row0l + 3 == col) v3 += 1.0f;
          }
          const int byte = col * 512 + (((rbase + row0l) * 2) ^ ((col & 7) << 4));
          uint2 val; val.x = pk2bf(v0, v1); val.y = pk2bf(v2, v3);
          *(uint2*)(&Tl[byte]) = val;
        }
      }
      __syncthreads();  // T_new visible before next iteration's reads
    } else {
      // final iteration: write res = I + S*T in fp32 straight to global
      #pragma unroll
      for (int mf = 0; mf < 4; ++mf) {
        #pragma unroll
        for (int nf = 0; nf < 4; ++nf) {
          const int col = 16 * nf + l15;
          const int row0 = rbase + 16 * mf + 4 * l4;
          #pragma unroll
          for (int j = 0; j < 4; ++j) {
            float v = acc[mf][nf][j];
            if (diagw && mf == nf && (16 * mf + 4 * l4 + j == col)) v += 1.0f;
            outb[(size_t)(row0 + j) * NN + col] = v;
          }
        }
      }
    }
  }
}

extern "C" void kernel_launch(void* const* d_in, const int* in_sizes, int n_in,
                              void* d_out, int out_size, void* d_ws, size_t ws_size,
                              hipStream_t stream) {
  const float* w = (const float*)d_in[0];
  float* out = (float*)d_out;
  unsigned short* sws = (unsigned short*)d_ws;  // needs 512*256*256*2 = 64 MB
  skew_prep_kernel<<<dim3(NB * 10), dim3(256), 0, stream>>>(w, sws);
  expm_main_kernel<<<dim3(NB * 4), dim3(256), 0, stream>>>(sws, out);
}

// Round 3
// 164.933 us; speedup vs baseline: 1.7649x; 1.2186x over previous
//
#include <hip/hip_runtime.h>
#include <hip/hip_bf16.h>

// BatchedExponentialOrthogonalization: res = sum_{i=0}^{6} S^i / i!,  S = 0.5(w - w^T)
// w: (512, 256, 256) fp32.  Horner: T = I + S/6; then T = I + (S/k)*T for k=5,4,3,2,1.
// prep: 5120 tile-pair blocks build S in bf16 into d_ws (64 MB), reading w exactly once.
// main: per (batch, 64-col block) workgroup, 4 waves; wave wv holds S rows
// [64wv,64wv+64) as MFMA A-fragments in registers for all 5 iterations; T lives in
// LDS transposed [col][k] bf16 with XOR bank swizzle. XCD-aware block mapping puts
// all 4 col-blocks of a batch on one XCD so S is fetched from HBM once per batch.
// launch_bounds(256,1): round-2's (256,2) capped regs at 128V and spilled the
// A-fragments (WRITE_SIZE 348MB vs 134MB output) -> scratch-latency-bound.

#define NB 512
#define NN 256

typedef __attribute__((ext_vector_type(8))) short bf16x8;
typedef __attribute__((ext_vector_type(4))) float f32x4;

__device__ __forceinline__ unsigned short f2bf(float x) {
  union { float f; unsigned int u; } v; v.f = x;
  unsigned int r = v.u + 0x7fffu + ((v.u >> 16) & 1u);  // RTNE
  return (unsigned short)(r >> 16);
}
__device__ __forceinline__ float bf2f(unsigned short u) {
  union { unsigned int u; float f; } v; v.u = ((unsigned int)u) << 16; return v.f;
}
__device__ __forceinline__ unsigned int pk2bf(float lo, float hi) {
  __hip_bfloat162 h;
  h.x = __float2bfloat16(lo);
  h.y = __float2bfloat16(hi);
  union { __hip_bfloat162 h; unsigned int u; } c; c.h = h;
  return c.u;
}

// ---------------- prep: S = 0.5*(w - w^T) in bf16; one block per 64x64 tile-pair ----
__global__ __launch_bounds__(256) void skew_prep_kernel(const float* __restrict__ w,
                                                        unsigned short* __restrict__ s) {
  static const int TI[10] = {0, 0, 0, 0, 1, 1, 1, 2, 2, 3};
  static const int TJ[10] = {0, 1, 2, 3, 1, 2, 3, 2, 3, 3};
  const int blk = blockIdx.x;
  const int b = blk / 10;
  const int p = blk - b * 10;
  const int ti = TI[p], tj = TJ[p];
  const float* wb = w + (size_t)b * NN * NN;
  unsigned short* sb = s + (size_t)b * NN * NN;
  __shared__ float ta[64][65];
  __shared__ float tb[64][65];
  const int tid = threadIdx.x;
  const int r = tid >> 4;        // 0..15 row group base (we loop 4 row-strides of 16)
  const int c4 = tid & 15;       // float4 column index

  #pragma unroll
  for (int e = 0; e < 4; ++e) {
    const int rr = e * 16 + r;
    float4 v = *(const float4*)&wb[(size_t)(ti * 64 + rr) * NN + tj * 64 + c4 * 4];
    ta[rr][c4 * 4 + 0] = v.x; ta[rr][c4 * 4 + 1] = v.y;
    ta[rr][c4 * 4 + 2] = v.z; ta[rr][c4 * 4 + 3] = v.w;
  }
  if (ti != tj) {
    #pragma unroll
    for (int e = 0; e < 4; ++e) {
      const int rr = e * 16 + r;
      float4 v = *(const float4*)&wb[(size_t)(tj * 64 + rr) * NN + ti * 64 + c4 * 4];
      tb[rr][c4 * 4 + 0] = v.x; tb[rr][c4 * 4 + 1] = v.y;
      tb[rr][c4 * 4 + 2] = v.z; tb[rr][c4 * 4 + 3] = v.w;
    }
  }
  __syncthreads();

  #pragma unroll
  for (int e = 0; e < 4; ++e) {
    const int rr = e * 16 + r;
    // tile (ti,tj): 0.5*(A[r][c] - B[c][r])   (B = A when diagonal)
    {
      unsigned short o[4];
      #pragma unroll
      for (int j = 0; j < 4; ++j) {
        const int cc = c4 * 4 + j;
        float av = ta[rr][cc];
        float bt = (ti == tj) ? ta[cc][rr] : tb[cc][rr];
        o[j] = f2bf(0.5f * (av - bt));
      }
      *(ushort4*)&sb[(size_t)(ti * 64 + rr) * NN + tj * 64 + c4 * 4] =
          make_ushort4(o[0], o[1], o[2], o[3]);
    }
    if (ti != tj) {
      unsigned short o[4];
      #pragma unroll
      for (int j = 0; j < 4; ++j) {
        const int cc = c4 * 4 + j;
        o[j] = f2bf(0.5f * (tb[rr][cc] - ta[cc][rr]));
      }
      *(ushort4*)&sb[(size_t)(tj * 64 + rr) * NN + ti * 64 + c4 * 4] =
          make_ushort4(o[0], o[1], o[2], o[3]);
    }
  }
}

// ---------------- main: Horner chain, S-rows in registers, T in LDS ------------------
__global__ __launch_bounds__(256, 1) void expm_main_kernel(const unsigned short* __restrict__ s,
                                                           float* __restrict__ out) {
  // XCD-aware decode: all 4 col-blocks of batch b share (g mod 8) -> same XCD L2.
  const int g = blockIdx.x;
  const int b = ((g >> 5) << 3) | (g & 7);
  const int cb = (g >> 3) & 3;
  const int tid = threadIdx.x;
  const int wv = tid >> 6;
  const int l = tid & 63;
  const int l15 = l & 15;
  const int l4 = l >> 4;

  const unsigned short* sb = s + (size_t)b * NN * NN;
  // T transposed: [col 0..63][k 0..255] bf16, byte addr = col*512 + ((2k) ^ ((col&7)<<4))
  __shared__ alignas(16) unsigned char Tl[64 * NN * 2];

  // --- A fragments: wave wv owns S rows [64*wv, 64*wv+64), persistent in registers ---
  bf16x8 a[4][8];
  const int rbase = wv * 64;
  #pragma unroll
  for (int mf = 0; mf < 4; ++mf) {
    const bf16x8* p = (const bf16x8*)(sb + (size_t)(rbase + 16 * mf + l15) * NN);
    #pragma unroll
    for (int ks = 0; ks < 8; ++ks) a[mf][ks] = p[4 * ks + l4];
  }

  // --- T init from registers: T[k][gcol] = (k==gcol) - S[gcol][k]/6 (skew symmetry).
  // Only wave cb holds rows gcol = cb*64 .. cb*64+63 in its A fragments.
  if (wv == cb) {
    #pragma unroll
    for (int mf = 0; mf < 4; ++mf) {
      const int lc = 16 * mf + l15;          // local col in T == local row in this wave
      const int gcol = rbase + lc;           // global col (== global row held)
      const int swz = (lc & 7) << 4;
      #pragma unroll
      for (int ks = 0; ks < 8; ++ks) {
        const bf16x8 fr = a[mf][ks];
        const int k0 = 32 * ks + 8 * l4;     // global k of fr[0]
        unsigned int pk[4];
        #pragma unroll
        for (int q = 0; q < 4; ++q) {
          float v0 = (-1.0f / 6.0f) * bf2f((unsigned short)fr[2 * q]);
          float v1 = (-1.0f / 6.0f) * bf2f((unsigned short)fr[2 * q + 1]);
          if (k0 + 2 * q == gcol) v0 += 1.0f;
          if (k0 + 2 * q + 1 == gcol) v1 += 1.0f;
          pk[q] = pk2bf(v0, v1);
        }
        const int byte = lc * 512 + ((2 * k0) ^ swz);
        uint4 val; val.x = pk[0]; val.y = pk[1]; val.z = pk[2]; val.w = pk[3];
        *(uint4*)(&Tl[byte]) = val;
      }
    }
  }
  __syncthreads();

  float* const outb = out + (size_t)b * NN * NN + cb * 64;
  const bool diagw = (wv == cb);

  for (int it = 0; it < 5; ++it) {
    const float coef = (it == 0) ? 0.2f : (it == 1) ? 0.25f : (it == 2) ? (1.0f / 3.0f)
                     : (it == 3) ? 0.5f : 1.0f;
    f32x4 acc[4][4];
    #pragma unroll
    for (int mf = 0; mf < 4; ++mf)
      #pragma unroll
      for (int nf = 0; nf < 4; ++nf) {
        f32x4 z = {0.0f, 0.0f, 0.0f, 0.0f};
        acc[mf][nf] = z;
      }

    #pragma unroll
    for (int ks = 0; ks < 8; ++ks) {
      bf16x8 bfr[4];
      #pragma unroll
      for (int nf = 0; nf < 4; ++nf) {
        const int col = 16 * nf + l15;
        const int byte = col * 512 + (((32 * ks + 8 * l4) * 2) ^ ((col & 7) << 4));
        bfr[nf] = *(const bf16x8*)(&Tl[byte]);
      }
      #pragma unroll
      for (int mf = 0; mf < 4; ++mf)
        #pragma unroll
        for (int nf = 0; nf < 4; ++nf)
          acc[mf][nf] = __builtin_amdgcn_mfma_f32_16x16x32_bf16(a[mf][ks], bfr[nf], acc[mf][nf], 0, 0, 0);
    }
    __syncthreads();  // all waves done reading T_old
    if (it < 4) {
      #pragma unroll
      for (int mf = 0; mf < 4; ++mf) {
        #pragma unroll
        for (int nf = 0; nf < 4; ++nf) {
          const int col = 16 * nf + l15;
          const int row0l = 16 * mf + 4 * l4;  // local row (within wave's 64)
          float v0 = coef * acc[mf][nf][0];
          float v1 = coef * acc[mf][nf][1];
          float v2 = coef * acc[mf][nf][2];
          float v3 = coef * acc[mf][nf][3];
          if (diagw && mf == nf) {
            // identity possible only when global row == global col
            if (row0l + 0 == col) v0 += 1.0f;
            if (row0l + 1 == col) v1 += 1.0f;
            if (row0l + 2 == col) v2 += 1.0f;
            if (row0l + 3 == col) v3 += 1.0f;
          }
          const int byte = col * 512 + (((rbase + row0l) * 2) ^ ((col & 7) << 4));
          uint2 val; val.x = pk2bf(v0, v1); val.y = pk2bf(v2, v3);
          *(uint2*)(&Tl[byte]) = val;
        }
      }
      __syncthreads();  // T_new visible before next iteration's reads
    } else {
      // final iteration: write res = I + S*T in fp32 straight to global
      #pragma unroll
      for (int mf = 0; mf < 4; ++mf) {
        #pragma unroll
        for (int nf = 0; nf < 4; ++nf) {
          const int col = 16 * nf + l15;
          const int row0 = rbase + 16 * mf + 4 * l4;
          #pragma unroll
          for (int j = 0; j < 4; ++j) {
            float v = acc[mf][nf][j];
            if (diagw && mf == nf && (16 * mf + 4 * l4 + j == col)) v += 1.0f;
            outb[(size_t)(row0 + j) * NN + col] = v;
          }
        }
      }
    }
  }
}

extern "C" void kernel_launch(void* const* d_in, const int* in_sizes, int n_in,
                              void* d_out, int out_size, void* d_ws, size_t ws_size,
                              hipStream_t stream) {
  const float* w = (const float*)d_in[0];
  float* out = (float*)d_out;
  unsigned short* sws = (unsigned short*)d_ws;  // needs 512*256*256*2 = 64 MB
  skew_prep_kernel<<<dim3(NB * 10), dim3(256), 0, stream>>>(w, sws);
  expm_main_kernel<<<dim3(NB * 4), dim3(256), 0, stream>>>(sws, out);
}

// Round 4
// 122.947 us; speedup vs baseline: 2.3676x; 1.3415x over previous
//
#include <hip/hip_runtime.h>
#include <hip/hip_bf16.h>

// BatchedExponentialOrthogonalization: res = sum_{i=0}^{6} S^i / i!,  S = 0.5(w - w^T)
// w: (512, 256, 256) fp32.  Horner: T = I + S/6; then T = I + (S/k)*T for k=5,4,3,2,1.
// prep: 5120 tile-pair blocks build S in bf16 into d_ws (64 MB), reading w exactly once.
// main: per (batch, 64-col block) workgroup, 4 waves; wave wv holds S rows
// [64wv,64wv+64) as MFMA A-fragments in registers for all 5 iterations; T double-
// buffered in LDS transposed [col][k] bf16 with XOR bank swizzle (one barrier/iter).
// nf split into 2 passes (acc 32 regs) so total unified regs fit 2 waves/SIMD ->
// 2 blocks/CU co-resident (round-3: (256,1) gave 1 block/CU, occupancy 11%).

#define NB 512
#define NN 256

typedef __attribute__((ext_vector_type(8))) short bf16x8;
typedef __attribute__((ext_vector_type(4))) float f32x4;

__device__ __forceinline__ unsigned short f2bf(float x) {
  union { float f; unsigned int u; } v; v.f = x;
  unsigned int r = v.u + 0x7fffu + ((v.u >> 16) & 1u);  // RTNE
  return (unsigned short)(r >> 16);
}
__device__ __forceinline__ float bf2f(unsigned short u) {
  union { unsigned int u; float f; } v; v.u = ((unsigned int)u) << 16; return v.f;
}
__device__ __forceinline__ unsigned int pk2bf(float lo, float hi) {
  __hip_bfloat162 h;
  h.x = __float2bfloat16(lo);
  h.y = __float2bfloat16(hi);
  union { __hip_bfloat162 h; unsigned int u; } c; c.h = h;
  return c.u;
}

// ---------------- prep: S = 0.5*(w - w^T) in bf16; one block per 64x64 tile-pair ----
__global__ __launch_bounds__(256) void skew_prep_kernel(const float* __restrict__ w,
                                                        unsigned short* __restrict__ s) {
  static const int TI[10] = {0, 0, 0, 0, 1, 1, 1, 2, 2, 3};
  static const int TJ[10] = {0, 1, 2, 3, 1, 2, 3, 2, 3, 3};
  const int blk = blockIdx.x;
  const int b = blk / 10;
  const int p = blk - b * 10;
  const int ti = TI[p], tj = TJ[p];
  const float* wb = w + (size_t)b * NN * NN;
  unsigned short* sb = s + (size_t)b * NN * NN;
  __shared__ float ta[64][65];
  __shared__ float tb[64][65];
  const int tid = threadIdx.x;
  const int r = tid >> 4;
  const int c4 = tid & 15;

  #pragma unroll
  for (int e = 0; e < 4; ++e) {
    const int rr = e * 16 + r;
    float4 v = *(const float4*)&wb[(size_t)(ti * 64 + rr) * NN + tj * 64 + c4 * 4];
    ta[rr][c4 * 4 + 0] = v.x; ta[rr][c4 * 4 + 1] = v.y;
    ta[rr][c4 * 4 + 2] = v.z; ta[rr][c4 * 4 + 3] = v.w;
  }
  if (ti != tj) {
    #pragma unroll
    for (int e = 0; e < 4; ++e) {
      const int rr = e * 16 + r;
      float4 v = *(const float4*)&wb[(size_t)(tj * 64 + rr) * NN + ti * 64 + c4 * 4];
      tb[rr][c4 * 4 + 0] = v.x; tb[rr][c4 * 4 + 1] = v.y;
      tb[rr][c4 * 4 + 2] = v.z; tb[rr][c4 * 4 + 3] = v.w;
    }
  }
  __syncthreads();

  #pragma unroll
  for (int e = 0; e < 4; ++e) {
    const int rr = e * 16 + r;
    {
      unsigned short o[4];
      #pragma unroll
      for (int j = 0; j < 4; ++j) {
        const int cc = c4 * 4 + j;
        float av = ta[rr][cc];
        float bt = (ti == tj) ? ta[cc][rr] : tb[cc][rr];
        o[j] = f2bf(0.5f * (av - bt));
      }
      *(ushort4*)&sb[(size_t)(ti * 64 + rr) * NN + tj * 64 + c4 * 4] =
          make_ushort4(o[0], o[1], o[2], o[3]);
    }
    if (ti != tj) {
      unsigned short o[4];
      #pragma unroll
      for (int j = 0; j < 4; ++j) {
        const int cc = c4 * 4 + j;
        o[j] = f2bf(0.5f * (tb[rr][cc] - ta[cc][rr]));
      }
      *(ushort4*)&sb[(size_t)(tj * 64 + rr) * NN + ti * 64 + c4 * 4] =
          make_ushort4(o[0], o[1], o[2], o[3]);
    }
  }
}

// ---------------- main: Horner chain, S-rows in registers, T double-buffered in LDS --
__global__ __launch_bounds__(256, 2) void expm_main_kernel(const unsigned short* __restrict__ s,
                                                           float* __restrict__ out) {
  // XCD-aware decode: all 4 col-blocks of batch b share (g mod 8) -> same XCD L2.
  const int g = blockIdx.x;
  const int b = ((g >> 5) << 3) | (g & 7);
  const int cb = (g >> 3) & 3;
  const int tid = threadIdx.x;
  const int wv = tid >> 6;
  const int l = tid & 63;
  const int l15 = l & 15;
  const int l4 = l >> 4;

  const unsigned short* sb = s + (size_t)b * NN * NN;
  // T buffers: [col 0..63][k 0..255] bf16, byte addr = col*512 + ((2k) ^ ((col&7)<<4))
  __shared__ alignas(16) unsigned char Tl[2][64 * NN * 2];

  // --- A fragments: wave wv owns S rows [64*wv, 64*wv+64), persistent in registers ---
  bf16x8 a[4][8];
  const int rbase = wv * 64;
  #pragma unroll
  for (int mf = 0; mf < 4; ++mf) {
    const bf16x8* p = (const bf16x8*)(sb + (size_t)(rbase + 16 * mf + l15) * NN);
    #pragma unroll
    for (int ks = 0; ks < 8; ++ks) a[mf][ks] = p[4 * ks + l4];
  }

  // --- T init into buf0 from registers: T[k][gcol] = (k==gcol) - S[gcol][k]/6. ---
  if (wv == cb) {
    #pragma unroll
    for (int mf = 0; mf < 4; ++mf) {
      const int lc = 16 * mf + l15;
      const int gcol = rbase + lc;
      const int swz = (lc & 7) << 4;
      #pragma unroll
      for (int ks = 0; ks < 8; ++ks) {
        const bf16x8 fr = a[mf][ks];
        const int k0 = 32 * ks + 8 * l4;
        unsigned int pk[4];
        #pragma unroll
        for (int q = 0; q < 4; ++q) {
          float v0 = (-1.0f / 6.0f) * bf2f((unsigned short)fr[2 * q]);
          float v1 = (-1.0f / 6.0f) * bf2f((unsigned short)fr[2 * q + 1]);
          if (k0 + 2 * q == gcol) v0 += 1.0f;
          if (k0 + 2 * q + 1 == gcol) v1 += 1.0f;
          pk[q] = pk2bf(v0, v1);
        }
        const int byte = lc * 512 + ((2 * k0) ^ swz);
        uint4 val; val.x = pk[0]; val.y = pk[1]; val.z = pk[2]; val.w = pk[3];
        *(uint4*)(&Tl[0][byte]) = val;
      }
    }
  }
  __syncthreads();

  float* const outb = out + (size_t)b * NN * NN + cb * 64;
  const bool diagw = (wv == cb);

  #pragma unroll
  for (int it = 0; it < 5; ++it) {
    const int rd = it & 1;        // compile-time after unroll
    const int wr = rd ^ 1;
    const float coef = (it == 0) ? 0.2f : (it == 1) ? 0.25f : (it == 2) ? (1.0f / 3.0f)
                     : (it == 3) ? 0.5f : 1.0f;
    #pragma unroll
    for (int p = 0; p < 2; ++p) {
      f32x4 acc[4][2];
      #pragma unroll
      for (int mf = 0; mf < 4; ++mf)
        #pragma unroll
        for (int pn = 0; pn < 2; ++pn) {
          f32x4 z = {0.0f, 0.0f, 0.0f, 0.0f};
          acc[mf][pn] = z;
        }

      #pragma unroll
      for (int ks = 0; ks < 8; ++ks) {
        bf16x8 bfr[2];
        #pragma unroll
        for (int pn = 0; pn < 2; ++pn) {
          const int col = 16 * (2 * p + pn) + l15;
          const int byte = col * 512 + (((32 * ks + 8 * l4) * 2) ^ ((col & 7) << 4));
          bfr[pn] = *(const bf16x8*)(&Tl[rd][byte]);
        }
        #pragma unroll
        for (int mf = 0; mf < 4; ++mf)
          #pragma unroll
          for (int pn = 0; pn < 2; ++pn)
            acc[mf][pn] = __builtin_amdgcn_mfma_f32_16x16x32_bf16(a[mf][ks], bfr[pn], acc[mf][pn], 0, 0, 0);
      }

      if (it < 4) {
        // write this pass's T_new columns into the other buffer (no barrier needed:
        // reads target Tl[rd], writes target Tl[wr])
        #pragma unroll
        for (int mf = 0; mf < 4; ++mf) {
          #pragma unroll
          for (int pn = 0; pn < 2; ++pn) {
            const int nf = 2 * p + pn;
            const int col = 16 * nf + l15;
            const int row0l = 16 * mf + 4 * l4;
            float v0 = coef * acc[mf][pn][0];
            float v1 = coef * acc[mf][pn][1];
            float v2 = coef * acc[mf][pn][2];
            float v3 = coef * acc[mf][pn][3];
            if (diagw && mf == nf) {
              if (row0l + 0 == col) v0 += 1.0f;
              if (row0l + 1 == col) v1 += 1.0f;
              if (row0l + 2 == col) v2 += 1.0f;
              if (row0l + 3 == col) v3 += 1.0f;
            }
            const int byte = col * 512 + (((rbase + row0l) * 2) ^ ((col & 7) << 4));
            uint2 val; val.x = pk2bf(v0, v1); val.y = pk2bf(v2, v3);
            *(uint2*)(&Tl[wr][byte]) = val;
          }
        }
      } else {
        // final iteration: res = I + S*T in fp32 straight to global
        #pragma unroll
        for (int mf = 0; mf < 4; ++mf) {
          #pragma unroll
          for (int pn = 0; pn < 2; ++pn) {
            const int nf = 2 * p + pn;
            const int col = 16 * nf + l15;
            const int row0 = rbase + 16 * mf + 4 * l4;
            #pragma unroll
            for (int j = 0; j < 4; ++j) {
              float v = acc[mf][pn][j];
              if (diagw && mf == nf && (16 * mf + 4 * l4 + j == col)) v += 1.0f;
              outb[(size_t)(row0 + j) * NN + col] = v;
            }
          }
        }
      }
    }
    if (it < 4) __syncthreads();  // T_new complete before next iteration reads it
  }
}

extern "C" void kernel_launch(void* const* d_in, const int* in_sizes, int n_in,
                              void* d_out, int out_size, void* d_ws, size_t ws_size,
                              hipStream_t stream) {
  const float* w = (const float*)d_in[0];
  float* out = (float*)d_out;
  unsigned short* sws = (unsigned short*)d_ws;  // needs 512*256*256*2 = 64 MB
  skew_prep_kernel<<<dim3(NB * 10), dim3(256), 0, stream>>>(w, sws);
  expm_main_kernel<<<dim3(NB * 4), dim3(256), 0, stream>>>(sws, out);
}